// Round 12
// baseline (206.845 us; speedup 1.0000x reference)
//
#include <hip/hip_runtime.h>
#include <hip/hip_bf16.h>

typedef unsigned short u16;
typedef unsigned int u32;
typedef __attribute__((ext_vector_type(4))) float f32x4;
typedef __attribute__((ext_vector_type(8))) _Float16 f16x8;
typedef __attribute__((ext_vector_type(2))) __fp16 hp16x2;
typedef __attribute__((ext_vector_type(8))) unsigned short u16x8;

#define LRELU(x) ((x) > 0.f ? (x) : 0.01f * (x))

static __device__ __forceinline__ u16 f2h(float x) {
    _Float16 h = (_Float16)x;
    u16 r;
    __builtin_memcpy(&r, &h, 2);
    return r;
}
static __device__ __forceinline__ float h2f(u16 v) {
    _Float16 h;
    __builtin_memcpy(&h, &v, 2);
    return (float)h;
}

// ---------------- prep: w1 = W*a1, w2 = W*a2, Wt hi/lo fp16 transpose-split --
__global__ void k_prep(const float* __restrict__ W, const float* __restrict__ a,
                       u16* __restrict__ Wt_hi, u16* __restrict__ Wt_lo,
                       float* __restrict__ w1, float* __restrict__ w2) {
    int i = blockIdx.x, t = threadIdx.x;
    float x = W[i * 256 + t];
    float p1 = x * a[t];
    float p2 = x * a[256 + t];
#pragma unroll
    for (int off = 1; off < 64; off <<= 1) {
        p1 += __shfl_xor(p1, off);
        p2 += __shfl_xor(p2, off);
    }
    __shared__ float s1[4], s2[4];
    if ((t & 63) == 0) { s1[t >> 6] = p1; s2[t >> 6] = p2; }
    __syncthreads();
    if (t == 0) {
        w1[i] = s1[0] + s1[1] + s1[2] + s1[3];
        w2[i] = s2[0] + s2[1] + s2[2] + s2[3];
    }
    // transpose column i -> Wt row i, split hi/lo fp16
    float y = W[t * 256 + i];
    u16 hi = f2h(y);
    Wt_hi[i * 256 + t] = hi;
    Wt_lo[i * 256 + t] = f2h(y - h2f(hi));
}

// ---------------- per-batch max of f2 ---------------------------------------
__global__ void k_m(const float* __restrict__ f2, float* __restrict__ Mb) {
    int b = blockIdx.x, t = threadIdx.x;
    float m = -1e30f;
#pragma unroll
    for (int j = 0; j < 4; ++j) m = fmaxf(m, f2[b * 1024 + t + j * 256]);
#pragma unroll
    for (int off = 1; off < 64; off <<= 1) m = fmaxf(m, __shfl_xor(m, off));
    __shared__ float s[4];
    if ((t & 63) == 0) s[t >> 6] = m;
    __syncthreads();
    if (t == 0) Mb[b] = fmaxf(fmaxf(s[0], s[1]), fmaxf(s[2], s[3]));
}

// ---------------- k_h: ht = (inp @ W)^T fp16 (3-term split), + f1/f2 --------
// Block = 32 n-rows; 4 waves split f (64 each). Grid 1024 -> 4 blocks/CU.
__global__ __launch_bounds__(256, 4) void k_h(const float* __restrict__ inp,
                                              const u16* __restrict__ Wt_hi,
                                              const u16* __restrict__ Wt_lo,
                                              const float* __restrict__ w1,
                                              const float* __restrict__ w2,
                                              u16* __restrict__ ht,
                                              float* __restrict__ f1,
                                              float* __restrict__ f2) {
    __shared__ float sw1[256], sw2[256];
    int t = threadIdx.x, w = t >> 6, l = t & 63, lr = l & 15, lk = l >> 4;
    sw1[t] = w1[t];
    sw2[t] = w2[t];
    __syncthreads();
    int n0 = blockIdx.x * 32;
    int bb = n0 >> 10, nb0 = n0 & 1023;

    f32x4 acc[4][2];
#pragma unroll
    for (int i = 0; i < 4; ++i)
#pragma unroll
        for (int j = 0; j < 2; ++j)
#pragma unroll
            for (int r = 0; r < 4; ++r) acc[i][j][r] = 0.f;
    float d1[2] = {0.f, 0.f}, d2[2] = {0.f, 0.f};

    for (int kt = 0; kt < 8; ++kt) {
        int k0 = kt * 32 + lk * 8;
        f16x8 ah[4], al[4];
#pragma unroll
        for (int it = 0; it < 4; ++it) {
            int f = w * 64 + it * 16 + lr;
            ah[it] = *(const f16x8*)&Wt_hi[f * 256 + k0];
            al[it] = *(const f16x8*)&Wt_lo[f * 256 + k0];
        }
        f32x4 c1a = *(const f32x4*)&sw1[k0];
        f32x4 c1b = *(const f32x4*)&sw1[k0 + 4];
        f32x4 c2a = *(const f32x4*)&sw2[k0];
        f32x4 c2b = *(const f32x4*)&sw2[k0 + 4];
#pragma unroll
        for (int ci = 0; ci < 2; ++ci) {
            int n = n0 + ci * 16 + lr;
            f32x4 v0 = *(const f32x4*)&inp[n * 256 + k0];
            f32x4 v1 = *(const f32x4*)&inp[n * 256 + k0 + 4];
            d1[ci] += v0.x * c1a.x + v0.y * c1a.y + v0.z * c1a.z + v0.w * c1a.w +
                      v1.x * c1b.x + v1.y * c1b.y + v1.z * c1b.z + v1.w * c1b.w;
            d2[ci] += v0.x * c2a.x + v0.y * c2a.y + v0.z * c2a.z + v0.w * c2a.w +
                      v1.x * c2b.x + v1.y * c2b.y + v1.z * c2b.z + v1.w * c2b.w;
            u16x8 hv, lv;
#pragma unroll
            for (int j = 0; j < 4; ++j) {
                u16 h0 = f2h(v0[j]);
                hv[j] = h0;
                lv[j] = f2h(v0[j] - h2f(h0));
                u16 h1 = f2h(v1[j]);
                hv[j + 4] = h1;
                lv[j + 4] = f2h(v1[j] - h2f(h1));
            }
            f16x8 bh = *(f16x8*)&hv, bl = *(f16x8*)&lv;
#pragma unroll
            for (int it = 0; it < 4; ++it) {
                acc[it][ci] = __builtin_amdgcn_mfma_f32_16x16x32_f16(ah[it], bh, acc[it][ci], 0, 0, 0);
                acc[it][ci] = __builtin_amdgcn_mfma_f32_16x16x32_f16(ah[it], bl, acc[it][ci], 0, 0, 0);
                acc[it][ci] = __builtin_amdgcn_mfma_f32_16x16x32_f16(al[it], bh, acc[it][ci], 0, 0, 0);
            }
        }
    }
    // f1/f2: reduce over lk lanes; identical across waves -> wave 0 writes
#pragma unroll
    for (int ci = 0; ci < 2; ++ci) {
        d1[ci] += __shfl_xor(d1[ci], 16);
        d1[ci] += __shfl_xor(d1[ci], 32);
        d2[ci] += __shfl_xor(d2[ci], 16);
        d2[ci] += __shfl_xor(d2[ci], 32);
    }
    if (w == 0 && l < 16) {
#pragma unroll
        for (int ci = 0; ci < 2; ++ci) {
            f1[n0 + ci * 16 + l] = d1[ci];
            f2[n0 + ci * 16 + l] = d2[ci];
        }
    }
    // ht write (fp16)
#pragma unroll
    for (int it = 0; it < 4; ++it)
#pragma unroll
        for (int ci = 0; ci < 2; ++ci) {
            int col = nb0 + ci * 16 + lr;
#pragma unroll
            for (int r = 0; r < 4; ++r) {
                int F = w * 64 + it * 16 + lk * 4 + r;
                ht[(size_t)(bb * 256 + F) * 1024 + col] = f2h(acc[it][ci][r]);
            }
        }
}

// ---------------- attention: softmax(leaky(f1+f2)) @ h, elu -----------------
// Barrier-free: each wave owns 32 rows x 64 f, computes its P fragments in
// registers (redundant across the 4 f-waves), H read directly from L2. No LDS.
__global__ __launch_bounds__(256, 4) void k_attn(const u16* __restrict__ ht,
                                                 const float* __restrict__ f1,
                                                 const float* __restrict__ f2,
                                                 const float* __restrict__ Mb,
                                                 float* __restrict__ out) {
    int t = threadIdx.x, w = t >> 6, l = t & 63, lr = l & 15, lk = l >> 4;
    int g = blockIdx.x;
    int xcd = g & 7, idx = g >> 3;
    int b = xcd * 4 + (idx >> 5);
    int i0 = (idx & 31) * 32;

    const float L2E = 1.44269504f;
    const float* F2 = f2 + b * 1024;
    float Mv = Mb[b];
    float f1v0 = f1[b * 1024 + i0 + lr];
    float f1v1 = f1[b * 1024 + i0 + 16 + lr];
    float mb0 = LRELU(f1v0 + Mv) * L2E;
    float mb1 = LRELU(f1v1 + Mv) * L2E;
    float ls0 = 0.f, ls1 = 0.f;
    const u16* H = ht + (size_t)b * 262144;

    f32x4 acc[2][4];
#pragma unroll
    for (int i = 0; i < 2; ++i)
#pragma unroll
        for (int j = 0; j < 4; ++j)
#pragma unroll
            for (int r = 0; r < 4; ++r) acc[i][j][r] = 0.f;

    for (int jt = 0; jt < 16; ++jt) {
        int jc0 = jt * 64 + lk * 8;
        int jc1 = jc0 + 32;
        // H fragment loads (L2-resident), issued early
        f16x8 bh0[4], bh1[4];
#pragma unroll
        for (int ci = 0; ci < 4; ++ci) {
            const u16* Hp = H + (size_t)(w * 64 + ci * 16 + lr) * 1024;
            bh0[ci] = *(const f16x8*)&Hp[jc0];
            bh1[ci] = *(const f16x8*)&Hp[jc1];
        }
        // P fragments in registers (redundant per wave; covers both rowgroups)
        f32x4 fa0 = *(const f32x4*)&F2[jc0];
        f32x4 fb0 = *(const f32x4*)&F2[jc0 + 4];
        f32x4 fa1 = *(const f32x4*)&F2[jc1];
        f32x4 fb1 = *(const f32x4*)&F2[jc1 + 4];
        union { f16x8 v; hp16x2 h[4]; } p00, p01, p10, p11;
        float pt0[8], pt1[8];
#pragma unroll
        for (int jj = 0; jj < 8; ++jj) {
            float fv = (jj < 4) ? fa0[jj] : fb0[jj - 4];
            float e0 = f1v0 + fv, e1 = f1v1 + fv;
            e0 = fmaxf(e0, 0.01f * e0);
            e1 = fmaxf(e1, 0.01f * e1);
            float q0 = __builtin_amdgcn_exp2f(fmaf(e0, L2E, -mb0));
            float q1 = __builtin_amdgcn_exp2f(fmaf(e1, L2E, -mb1));
            ls0 += q0; ls1 += q1;
            pt0[jj] = q0; pt1[jj] = q1;
        }
#pragma unroll
        for (int jj = 0; jj < 4; ++jj) {
            p00.h[jj] = __builtin_amdgcn_cvt_pkrtz(pt0[2 * jj], pt0[2 * jj + 1]);
            p10.h[jj] = __builtin_amdgcn_cvt_pkrtz(pt1[2 * jj], pt1[2 * jj + 1]);
        }
#pragma unroll
        for (int jj = 0; jj < 8; ++jj) {
            float fv = (jj < 4) ? fa1[jj] : fb1[jj - 4];
            float e0 = f1v0 + fv, e1 = f1v1 + fv;
            e0 = fmaxf(e0, 0.01f * e0);
            e1 = fmaxf(e1, 0.01f * e1);
            float q0 = __builtin_amdgcn_exp2f(fmaf(e0, L2E, -mb0));
            float q1 = __builtin_amdgcn_exp2f(fmaf(e1, L2E, -mb1));
            ls0 += q0; ls1 += q1;
            pt0[jj] = q0; pt1[jj] = q1;
        }
#pragma unroll
        for (int jj = 0; jj < 4; ++jj) {
            p01.h[jj] = __builtin_amdgcn_cvt_pkrtz(pt0[2 * jj], pt0[2 * jj + 1]);
            p11.h[jj] = __builtin_amdgcn_cvt_pkrtz(pt1[2 * jj], pt1[2 * jj + 1]);
        }
        // MFMA: acc[rg][ci] += P[rg] x H fragments
#pragma unroll
        for (int ci = 0; ci < 4; ++ci) {
            acc[0][ci] = __builtin_amdgcn_mfma_f32_16x16x32_f16(p00.v, bh0[ci], acc[0][ci], 0, 0, 0);
            acc[1][ci] = __builtin_amdgcn_mfma_f32_16x16x32_f16(p10.v, bh0[ci], acc[1][ci], 0, 0, 0);
            acc[0][ci] = __builtin_amdgcn_mfma_f32_16x16x32_f16(p01.v, bh1[ci], acc[0][ci], 0, 0, 0);
            acc[1][ci] = __builtin_amdgcn_mfma_f32_16x16x32_f16(p11.v, bh1[ci], acc[1][ci], 0, 0, 0);
        }
    }

    // full row sums per wave: reduce over the 4 lk groups (j-partition)
    ls0 += __shfl_xor(ls0, 16);
    ls0 += __shfl_xor(ls0, 32);
    ls1 += __shfl_xor(ls1, 16);
    ls1 += __shfl_xor(ls1, 32);

#pragma unroll
    for (int it = 0; it < 2; ++it) {
        float lsv = (it == 0) ? ls0 : ls1;
        float sums[4];
#pragma unroll
        for (int r = 0; r < 4; ++r) sums[r] = __shfl(lsv, lk * 4 + r);
#pragma unroll
        for (int ci = 0; ci < 4; ++ci) {
            int col = w * 64 + ci * 16 + lr;
            int rowg = b * 1024 + i0 + it * 16 + lk * 4;
#pragma unroll
            for (int r = 0; r < 4; ++r) {
                float v = acc[it][ci][r] / sums[r];
                v = v > 0.f ? v : (__expf(v) - 1.f);
                out[(size_t)(rowg + r) * 256 + col] = v;
            }
        }
    }
}

extern "C" void kernel_launch(void* const* d_in, const int* in_sizes, int n_in,
                              void* d_out, int out_size, void* d_ws, size_t ws_size,
                              hipStream_t stream) {
    const float* inp = (const float*)d_in[0];
    const float* W = (const float*)d_in[1];
    const float* a = (const float*)d_in[2];
    float* out = (float*)d_out;

    char* ws = (char*)d_ws;
    u16* ht = (u16*)(ws + 0);               // 16,777,216 B (fp16)
    u16* Wt_hi = (u16*)(ws + 16777216);     // 131,072 B
    u16* Wt_lo = (u16*)(ws + 16908288);     // 131,072 B
    float* w1 = (float*)(ws + 17039360);    // 1,024 B
    float* w2 = (float*)(ws + 17040384);    // 1,024 B
    float* f1 = (float*)(ws + 17041408);    // 131,072 B
    float* f2 = (float*)(ws + 17172480);    // 131,072 B
    float* Mb = (float*)(ws + 17303552);    // 128 B

    k_prep<<<256, 256, 0, stream>>>(W, a, Wt_hi, Wt_lo, w1, w2);
    k_h<<<1024, 256, 0, stream>>>(inp, Wt_hi, Wt_lo, w1, w2, ht, f1, f2);
    k_m<<<32, 256, 0, stream>>>(f2, Mb);
    k_attn<<<1024, 256, 0, stream>>>(ht, f1, f2, Mb, out);
}